// Round 10
// baseline (134.268 us; speedup 1.0000x reference)
//
#include <hip/hip_runtime.h>
#include <math.h>

#define N 4096
#define D 256
#define NPOS 32768
#define TEMP 0.07f
#define INVT (1.0f / 0.07f)
#define BIGF 3.0e38f

#define RQ 5.5f                      // quantization range [-RQ, RQ]
#define QS (255.0f / (2.0f * RQ))    // f32 -> u8 scale
#define DEQ (2.0f * RQ / 255.0f)     // u8-units -> f32

#define NT 64                        // 64x64 tiles per dim
#define NTRI (NT * (NT + 1) / 2)     // 2080 triangle blocks
#define KC 32                        // u32 (k4) per D-chunk (=128 dims), 2 chunks
#define LP 68                        // LDS row stride in u32 (16B-aligned pad)

// workspace layout (floats):
// [0 .. N*64)         pmin[r][c]  (r = row, c = 64-col-tile)  row-major
// [N*64 .. 2*N*64)    psum[r][c]
// [2*N*64 .. +N)      t[r]
// [.. +1]             loss accumulator (float)
// [.. +1]             ticket counter (uint)
// [WS_XQ ..)          xq: N*(D/4) u32 of packed u8 quants
#define WS_PMIN 0
#define WS_PSUM (N * NT)
#define WS_T    (2 * N * NT)
#define WS_ACC  (2 * N * NT + N)
#define WS_CNT  (2 * N * NT + N + 1)
#define WS_XQ   (2 * N * NT + N + 4)   // 16B-aligned

__device__ __forceinline__ void sad_acc(unsigned a, unsigned b, unsigned& c) {
#if __has_builtin(__builtin_amdgcn_sad_u8)
    c = __builtin_amdgcn_sad_u8(a, b, c);
#else
    asm("v_sad_u8 %0, %1, %2, %0" : "+v"(c) : "v"(a), "v"(b));
#endif
}

__device__ __forceinline__ unsigned quant1(float v) {
    const float f = fminf(fmaxf((v + RQ) * QS, 0.0f), 255.0f);
    return (unsigned)__float2uint_rn(f);
}

// quantize f32 -> packed u8 (4/u32), and zero acc/ticket
__global__ __launch_bounds__(256)
void cvt_init_k(const float* __restrict__ x, unsigned* __restrict__ xq,
                float* __restrict__ acc, unsigned* __restrict__ cnt) {
    const int i = blockIdx.x * 256 + threadIdx.x;  // over N*D/4
    const float4 v = ((const float4*)x)[i];
    const unsigned q = quant1(v.x) | (quant1(v.y) << 8) |
                       (quant1(v.z) << 16) | (quant1(v.w) << 24);
    xq[i] = q;
    if (i == 0) { *acc = 0.0f; *cnt = 0u; }
}

// 64x64 tile, ONE wave per block (2080 blocks -> fine-grained load balance,
// ~9 blocks/CU resident via 17.4 KB LDS for cross-wave latency hiding).
// 8x8 micro-tile per lane, u8 SAD inner loop. LDS [k4][m] stride-68:
// frag b128 reads are 8 distinct addrs spanning all 32 banks (conflict-free).
__global__ __launch_bounds__(64, 2)
void dist_tile_k(const unsigned* __restrict__ xq,
                 float* __restrict__ pmin, float* __restrict__ psum) {
    // triangular decode: blockIdx.x -> (bm, bn), bm <= bn
    const int tt = blockIdx.x;
    const int u_ = (NTRI - 1) - tt;
    int r = (int)((sqrtf((float)(8 * u_ + 1)) - 1.0f) * 0.5f);
    while (r * (r + 1) / 2 > u_) --r;
    while ((r + 1) * (r + 2) / 2 <= u_) ++r;
    const int bm = (NT - 1) - r;                      // row tile
    const int bn = (NT - 1) - (u_ - r * (r + 1) / 2); // col tile
    const bool diag = (bm == bn);

    const int lane = threadIdx.x;   // 0..63
    const int tx = lane & 7;
    const int ty = lane >> 3;

    __shared__ unsigned As[KC][LP];  // 8.7 KB
    __shared__ unsigned Bs[KC][LP];  // 8.7 KB

    unsigned uacc[2][2][4][4];
#pragma unroll
    for (int rh = 0; rh < 2; ++rh)
#pragma unroll
        for (int ch = 0; ch < 2; ++ch)
#pragma unroll
            for (int i = 0; i < 4; ++i)
#pragma unroll
                for (int j = 0; j < 4; ++j) uacc[rh][ch][i][j] = 0u;

    const int rowA0 = bm * 64;
    const int rowB0 = bn * 64;

    // staging: lane (u = lane&7 -> uint4 col, r0 = lane>>3), rows r0+8c
    const int su = lane & 7;
    const int r0 = lane >> 3;
    const uint4* gA = (const uint4*)xq + (size_t)(rowA0 + r0) * 16 + su;
    const uint4* gB = (const uint4*)xq + (size_t)(rowB0 + r0) * 16 + su;

    const int aoff = ty * 4;
    const int boff = tx * 4;

    for (int chk = 0; chk < 2; ++chk) {
        const int gbase = chk * 8;
        uint4 la[8], lb[8];
#pragma unroll
        for (int c = 0; c < 8; ++c) la[c] = gA[gbase + (size_t)c * 128];  // row r0+8c
#pragma unroll
        for (int c = 0; c < 8; ++c) lb[c] = gB[gbase + (size_t)c * 128];
        __syncthreads();  // previous chunk's reads done before overwrite
#pragma unroll
        for (int c = 0; c < 8; ++c) {
            const int rr = r0 + 8 * c;
            As[su * 4 + 0][rr] = la[c].x; As[su * 4 + 1][rr] = la[c].y;
            As[su * 4 + 2][rr] = la[c].z; As[su * 4 + 3][rr] = la[c].w;
            Bs[su * 4 + 0][rr] = lb[c].x; Bs[su * 4 + 1][rr] = lb[c].y;
            Bs[su * 4 + 2][rr] = lb[c].z; Bs[su * 4 + 3][rr] = lb[c].w;
        }
        __syncthreads();

#pragma unroll 8
        for (int k4 = 0; k4 < KC; ++k4) {
            const uint4 alo = *(const uint4*)&As[k4][aoff];
            const uint4 ahi = *(const uint4*)&As[k4][aoff + 32];
            const uint4 blo = *(const uint4*)&Bs[k4][boff];
            const uint4 bhi = *(const uint4*)&Bs[k4][boff + 32];
            const unsigned av[2][4] = {{alo.x, alo.y, alo.z, alo.w},
                                       {ahi.x, ahi.y, ahi.z, ahi.w}};
            const unsigned bv[2][4] = {{blo.x, blo.y, blo.z, blo.w},
                                       {bhi.x, bhi.y, bhi.z, bhi.w}};
#pragma unroll
            for (int rh = 0; rh < 2; ++rh)
#pragma unroll
                for (int chq = 0; chq < 2; ++chq)
#pragma unroll
                    for (int i = 0; i < 4; ++i)
#pragma unroll
                        for (int j = 0; j < 4; ++j)
                            sad_acc(av[rh][i], bv[chq][j], uacc[rh][chq][i][j]);
        }
    }

    // dequantize to float
    float acc[2][2][4][4];
#pragma unroll
    for (int rh = 0; rh < 2; ++rh)
#pragma unroll
        for (int chq = 0; chq < 2; ++chq)
#pragma unroll
            for (int i = 0; i < 4; ++i)
#pragma unroll
                for (int j = 0; j < 4; ++j)
                    acc[rh][chq][i][j] = (float)uacc[rh][chq][i][j] * DEQ;

    // diagonal exclusion: poison self-distance (min skips it, exp -> 0)
    if (diag) {
#pragma unroll
        for (int rh = 0; rh < 2; ++rh)
#pragma unroll
            for (int chq = 0; chq < 2; ++chq)
#pragma unroll
                for (int i = 0; i < 4; ++i)
#pragma unroll
                    for (int j = 0; j < 4; ++j)
                        if (rh * 32 + ty * 4 + i == chq * 32 + tx * 4 + j)
                            acc[rh][chq][i][j] = BIGF;
    }

    // ---- row stats (always; bm <= bn): my 8 cols + shfl across tx lanes ----
    {
#pragma unroll
        for (int rh = 0; rh < 2; ++rh) {
#pragma unroll
            for (int i = 0; i < 4; ++i) {
                float mn = BIGF;
#pragma unroll
                for (int chq = 0; chq < 2; ++chq)
#pragma unroll
                    for (int j = 0; j < 4; ++j) mn = fminf(mn, acc[rh][chq][i][j]);
                mn = fminf(mn, __shfl_xor(mn, 1, 64));
                mn = fminf(mn, __shfl_xor(mn, 2, 64));
                mn = fminf(mn, __shfl_xor(mn, 4, 64));
                float s = 0.0f;
#pragma unroll
                for (int chq = 0; chq < 2; ++chq)
#pragma unroll
                    for (int j = 0; j < 4; ++j)
                        s += __expf((mn - acc[rh][chq][i][j]) * INVT);
                s += __shfl_xor(s, 1, 64);
                s += __shfl_xor(s, 2, 64);
                s += __shfl_xor(s, 4, 64);
                if (tx == 0) {
                    const size_t idx =
                        (size_t)(rowA0 + rh * 32 + ty * 4 + i) * NT + bn;
                    pmin[idx] = mn;
                    psum[idx] = s;
                }
            }
        }
    }

    // ---- col stats (iff bm < bn): my 8 rows + shfl across ty lanes ----
    if (!diag) {
#pragma unroll
        for (int chq = 0; chq < 2; ++chq) {
#pragma unroll
            for (int j = 0; j < 4; ++j) {
                float mn = BIGF;
#pragma unroll
                for (int rh = 0; rh < 2; ++rh)
#pragma unroll
                    for (int i = 0; i < 4; ++i) mn = fminf(mn, acc[rh][chq][i][j]);
                mn = fminf(mn, __shfl_xor(mn, 8, 64));
                mn = fminf(mn, __shfl_xor(mn, 16, 64));
                mn = fminf(mn, __shfl_xor(mn, 32, 64));
                float s = 0.0f;
#pragma unroll
                for (int rh = 0; rh < 2; ++rh)
#pragma unroll
                    for (int i = 0; i < 4; ++i)
                        s += __expf((mn - acc[rh][chq][i][j]) * INVT);
                s += __shfl_xor(s, 8, 64);
                s += __shfl_xor(s, 16, 64);
                s += __shfl_xor(s, 32, 64);
                if (ty == 0) {
                    const size_t idx =
                        (size_t)(rowB0 + chq * 32 + tx * 4 + j) * NT + bm;
                    pmin[idx] = mn;
                    psum[idx] = s;
                }
            }
        }
    }
}

// One wave per row: coalesced read of the 64 partials, shuffle reduce.
__global__ __launch_bounds__(256)
void row_stats_k(const float* __restrict__ pmin, const float* __restrict__ psum,
                 float* __restrict__ t) {
    const int r = blockIdx.x * 4 + (threadIdx.x >> 6);
    const int c = threadIdx.x & 63;
    const float pm = pmin[(size_t)r * NT + c];
    const float ps = psum[(size_t)r * NT + c];
    float mn = pm;
#pragma unroll
    for (int off = 32; off > 0; off >>= 1) mn = fminf(mn, __shfl_xor(mn, off, 64));
    float s = ps * __expf((mn - pm) * INVT);
#pragma unroll
    for (int off = 32; off > 0; off >>= 1) s += __shfl_xor(s, off, 64);
    if (c == 0) t[r] = TEMP * __logf(s) - mn;
}

// 1024 blocks x 4 waves x 8 pairs; batched index+data loads; block-level
// atomic + ticket: last block finalizes the loss.
__global__ __launch_bounds__(256)
void pair_fin_k(const float* __restrict__ x, const int* __restrict__ row,
                const int* __restrict__ col, const float* __restrict__ t,
                float* __restrict__ acc, unsigned* __restrict__ cnt,
                float* __restrict__ out) {
    const int lane = threadIdx.x & 63;
    const int wave = threadIdx.x >> 6;
    const int p0 = (blockIdx.x * 4 + wave) * 8;

    int rp[8], cp[8];
#pragma unroll
    for (int i = 0; i < 8; ++i) { rp[i] = row[p0 + i]; cp[i] = col[p0 + i]; }
    float4 a[8], b[8];
#pragma unroll
    for (int i = 0; i < 8; ++i) {
        a[i] = *(const float4*)&x[(size_t)rp[i] * D + lane * 4];
        b[i] = *(const float4*)&x[(size_t)cp[i] * D + lane * 4];
    }
    float wsum = 0.0f;
#pragma unroll
    for (int i = 0; i < 8; ++i) {
        float d = fabsf(a[i].x - b[i].x) + fabsf(a[i].y - b[i].y) +
                  fabsf(a[i].z - b[i].z) + fabsf(a[i].w - b[i].w);
#pragma unroll
        for (int off = 32; off > 0; off >>= 1) d += __shfl_xor(d, off, 64);
        if (lane == 0) wsum += d + t[rp[i]];
    }

    __shared__ float bs[4];
    if (lane == 0) bs[wave] = wsum;
    __syncthreads();
    if (threadIdx.x == 0) {
        const float tot = bs[0] + bs[1] + bs[2] + bs[3];
        atomicAdd(acc, tot);
        __threadfence();
        const unsigned tk = atomicAdd(cnt, 1u);
        if (tk == (unsigned)(gridDim.x - 1)) {
            const float v = atomicAdd(acc, 0.0f);  // coherent read
            out[0] = v * (1.0f / (float)NPOS);
        }
    }
}

extern "C" void kernel_launch(void* const* d_in, const int* in_sizes, int n_in,
                              void* d_out, int out_size, void* d_ws, size_t ws_size,
                              hipStream_t stream) {
    const float* x = (const float*)d_in[0];
    const int* row = (const int*)d_in[1];
    const int* col = (const int*)d_in[2];
    float* ws = (float*)d_ws;
    float* out = (float*)d_out;
    unsigned* xq = (unsigned*)(ws + WS_XQ);
    float* acc = ws + WS_ACC;
    unsigned* cnt = (unsigned*)(ws + WS_CNT);

    cvt_init_k<<<(N * D / 4) / 256, 256, 0, stream>>>(x, xq, acc, cnt);

    dist_tile_k<<<NTRI, 64, 0, stream>>>(xq, ws + WS_PMIN, ws + WS_PSUM);

    row_stats_k<<<N / 4, 256, 0, stream>>>(ws + WS_PMIN, ws + WS_PSUM, ws + WS_T);

    pair_fin_k<<<NPOS / 32, 256, 0, stream>>>(x, row, col, ws + WS_T, acc, cnt, out);
}

// Round 11
// 132.073 us; speedup vs baseline: 1.0166x; 1.0166x over previous
//
#include <hip/hip_runtime.h>
#include <math.h>

#define N 4096
#define D 256
#define NPOS 32768
#define TEMP 0.07f
#define INVT (1.0f / 0.07f)
#define BIGF 3.0e38f

#define RQ 5.5f                      // quantization range [-RQ, RQ]
#define QS (255.0f / (2.0f * RQ))    // f32 -> u8 scale
#define DEQ (2.0f * RQ / 255.0f)     // u8-units -> f32

#define NT 64                        // 64x64 tiles per dim
#define NTRI (NT * (NT + 1) / 2)     // 2080 triangle blocks
#define KC 16                        // u32 (k4) per D-chunk (=64 dims), 4 chunks
#define LP 68                        // LDS row stride in u32

// workspace layout (floats):
// [0 .. 2*N*64)       pstat[r][c] float2 (pmin, psum), r=row, c=64-col-tile
// [2*N*64 .. +N)      t[r]
// [.. +1]             loss accumulator (float)
// [.. +1]             ticket counter (uint)
// [WS_XQ ..)          xq: N*(D/4) u32 of packed u8 quants
#define WS_PSTAT 0
#define WS_T    (2 * N * NT)
#define WS_ACC  (2 * N * NT + N)
#define WS_CNT  (2 * N * NT + N + 1)
#define WS_XQ   (2 * N * NT + N + 4)   // 16B-aligned

__device__ __forceinline__ void sad_acc(unsigned a, unsigned b, unsigned& c) {
#if __has_builtin(__builtin_amdgcn_sad_u8)
    c = __builtin_amdgcn_sad_u8(a, b, c);
#else
    asm("v_sad_u8 %0, %1, %2, %0" : "+v"(c) : "v"(a), "v"(b));
#endif
}

__device__ __forceinline__ unsigned quant1(float v) {
    const float f = fminf(fmaxf((v + RQ) * QS, 0.0f), 255.0f);
    return (unsigned)__float2uint_rn(f);
}

// quantize f32 -> packed u8 (4/u32), and zero acc/ticket
__global__ __launch_bounds__(256)
void cvt_init_k(const float* __restrict__ x, unsigned* __restrict__ xq,
                float* __restrict__ acc, unsigned* __restrict__ cnt) {
    const int i = blockIdx.x * 256 + threadIdx.x;  // over N*D/4
    const float4 v = ((const float4*)x)[i];
    const unsigned q = quant1(v.x) | (quant1(v.y) << 8) |
                       (quant1(v.z) << 16) | (quant1(v.w) << 24);
    xq[i] = q;
    if (i == 0) { *acc = 0.0f; *cnt = 0u; }
}

// 64x64 tile, ONE wave per block. Single-wave workgroup: no s_barrier —
// per-chunk ordering via lgkmcnt(0) only (keeps vmcnt out of the drain).
// KC=16 -> LDS 8.7 KB (high residency); staging writes alias exactly 2-way
// (free); frag b128 reads conflict-free. u8 SAD inner loop (quarter-rate
// VALU is the structural ceiling: ~28 us device-wide for the half-matrix).
__global__ __launch_bounds__(64, 2)
void dist_tile_k(const unsigned* __restrict__ xq, float2* __restrict__ pstat) {
    // triangular decode: blockIdx.x -> (bm, bn), bm <= bn
    const int tt = blockIdx.x;
    const int u_ = (NTRI - 1) - tt;
    int r = (int)((sqrtf((float)(8 * u_ + 1)) - 1.0f) * 0.5f);
    while (r * (r + 1) / 2 > u_) --r;
    while ((r + 1) * (r + 2) / 2 <= u_) ++r;
    const int bm = (NT - 1) - r;                      // row tile
    const int bn = (NT - 1) - (u_ - r * (r + 1) / 2); // col tile
    const bool diag = (bm == bn);

    const int lane = threadIdx.x;   // 0..63
    const int tx = lane & 7;
    const int ty = lane >> 3;

    __shared__ unsigned As[KC][LP];  // 4.35 KB
    __shared__ unsigned Bs[KC][LP];  // 4.35 KB

    unsigned uacc[2][2][4][4];
#pragma unroll
    for (int rh = 0; rh < 2; ++rh)
#pragma unroll
        for (int ch = 0; ch < 2; ++ch)
#pragma unroll
            for (int i = 0; i < 4; ++i)
#pragma unroll
                for (int j = 0; j < 4; ++j) uacc[rh][ch][i][j] = 0u;

    const int rowA0 = bm * 64;
    const int rowB0 = bn * 64;

    // staging: su = lane&3 (uint4 col within chunk), r0 = lane>>2 (0..15),
    // rows r0+16c for c=0..3. Row = 16 uint4 in global.
    const int su = lane & 3;
    const int r0 = lane >> 2;
    const uint4* gA = (const uint4*)xq + (size_t)(rowA0 + r0) * 16 + su;
    const uint4* gB = (const uint4*)xq + (size_t)(rowB0 + r0) * 16 + su;

    const int aoff = ty * 4;
    const int boff = tx * 4;

    for (int chk = 0; chk < 4; ++chk) {
        uint4 la[4], lb[4];
#pragma unroll
        for (int c = 0; c < 4; ++c) la[c] = gA[chk * 4 + (size_t)c * 256];
#pragma unroll
        for (int c = 0; c < 4; ++c) lb[c] = gB[chk * 4 + (size_t)c * 256];
        // WAR: previous chunk's ds_reads retired before overwrite
        asm volatile("s_waitcnt lgkmcnt(0)" ::: "memory");
#pragma unroll
        for (int c = 0; c < 4; ++c) {
            const int rr = r0 + 16 * c;
            As[su * 4 + 0][rr] = la[c].x; As[su * 4 + 1][rr] = la[c].y;
            As[su * 4 + 2][rr] = la[c].z; As[su * 4 + 3][rr] = la[c].w;
            Bs[su * 4 + 0][rr] = lb[c].x; Bs[su * 4 + 1][rr] = lb[c].y;
            Bs[su * 4 + 2][rr] = lb[c].z; Bs[su * 4 + 3][rr] = lb[c].w;
        }
        // RAW: staging writes visible before fragment reads
        asm volatile("s_waitcnt lgkmcnt(0)" ::: "memory");

#pragma unroll
        for (int k4 = 0; k4 < KC; ++k4) {
            const uint4 alo = *(const uint4*)&As[k4][aoff];
            const uint4 ahi = *(const uint4*)&As[k4][aoff + 32];
            const uint4 blo = *(const uint4*)&Bs[k4][boff];
            const uint4 bhi = *(const uint4*)&Bs[k4][boff + 32];
            const unsigned av[2][4] = {{alo.x, alo.y, alo.z, alo.w},
                                       {ahi.x, ahi.y, ahi.z, ahi.w}};
            const unsigned bv[2][4] = {{blo.x, blo.y, blo.z, blo.w},
                                       {bhi.x, bhi.y, bhi.z, bhi.w}};
#pragma unroll
            for (int rh = 0; rh < 2; ++rh)
#pragma unroll
                for (int chq = 0; chq < 2; ++chq)
#pragma unroll
                    for (int i = 0; i < 4; ++i)
#pragma unroll
                        for (int j = 0; j < 4; ++j)
                            sad_acc(av[rh][i], bv[chq][j], uacc[rh][chq][i][j]);
        }
    }

    // dequantize to float
    float acc[2][2][4][4];
#pragma unroll
    for (int rh = 0; rh < 2; ++rh)
#pragma unroll
        for (int chq = 0; chq < 2; ++chq)
#pragma unroll
            for (int i = 0; i < 4; ++i)
#pragma unroll
                for (int j = 0; j < 4; ++j)
                    acc[rh][chq][i][j] = (float)uacc[rh][chq][i][j] * DEQ;

    // diagonal exclusion: poison self-distance (min skips it, exp -> 0)
    if (diag) {
#pragma unroll
        for (int rh = 0; rh < 2; ++rh)
#pragma unroll
            for (int chq = 0; chq < 2; ++chq)
#pragma unroll
                for (int i = 0; i < 4; ++i)
#pragma unroll
                    for (int j = 0; j < 4; ++j)
                        if (rh * 32 + ty * 4 + i == chq * 32 + tx * 4 + j)
                            acc[rh][chq][i][j] = BIGF;
    }

    // ---- row stats (always; bm <= bn): my 8 cols + shfl across tx lanes ----
#pragma unroll
    for (int rh = 0; rh < 2; ++rh) {
#pragma unroll
        for (int i = 0; i < 4; ++i) {
            float mn = BIGF;
#pragma unroll
            for (int chq = 0; chq < 2; ++chq)
#pragma unroll
                for (int j = 0; j < 4; ++j) mn = fminf(mn, acc[rh][chq][i][j]);
            mn = fminf(mn, __shfl_xor(mn, 1, 64));
            mn = fminf(mn, __shfl_xor(mn, 2, 64));
            mn = fminf(mn, __shfl_xor(mn, 4, 64));
            float s = 0.0f;
#pragma unroll
            for (int chq = 0; chq < 2; ++chq)
#pragma unroll
                for (int j = 0; j < 4; ++j)
                    s += __expf((mn - acc[rh][chq][i][j]) * INVT);
            s += __shfl_xor(s, 1, 64);
            s += __shfl_xor(s, 2, 64);
            s += __shfl_xor(s, 4, 64);
            if (tx == 0)
                pstat[(size_t)(rowA0 + rh * 32 + ty * 4 + i) * NT + bn] =
                    make_float2(mn, s);
        }
    }

    // ---- col stats (iff bm < bn): my 8 rows + shfl across ty lanes ----
    if (!diag) {
#pragma unroll
        for (int chq = 0; chq < 2; ++chq) {
#pragma unroll
            for (int j = 0; j < 4; ++j) {
                float mn = BIGF;
#pragma unroll
                for (int rh = 0; rh < 2; ++rh)
#pragma unroll
                    for (int i = 0; i < 4; ++i) mn = fminf(mn, acc[rh][chq][i][j]);
                mn = fminf(mn, __shfl_xor(mn, 8, 64));
                mn = fminf(mn, __shfl_xor(mn, 16, 64));
                mn = fminf(mn, __shfl_xor(mn, 32, 64));
                float s = 0.0f;
#pragma unroll
                for (int rh = 0; rh < 2; ++rh)
#pragma unroll
                    for (int i = 0; i < 4; ++i)
                        s += __expf((mn - acc[rh][chq][i][j]) * INVT);
                s += __shfl_xor(s, 8, 64);
                s += __shfl_xor(s, 16, 64);
                s += __shfl_xor(s, 32, 64);
                if (ty == 0)
                    pstat[(size_t)(rowB0 + chq * 32 + tx * 4 + j) * NT + bm] =
                        make_float2(mn, s);
            }
        }
    }
}

// One wave per row: coalesced float2 read of the 64 partials, shuffle reduce.
__global__ __launch_bounds__(256)
void row_stats_k(const float2* __restrict__ pstat, float* __restrict__ t) {
    const int r = blockIdx.x * 4 + (threadIdx.x >> 6);
    const int c = threadIdx.x & 63;
    const float2 p = pstat[(size_t)r * NT + c];
    float mn = p.x;
#pragma unroll
    for (int off = 32; off > 0; off >>= 1) mn = fminf(mn, __shfl_xor(mn, off, 64));
    float s = p.y * __expf((mn - p.x) * INVT);
#pragma unroll
    for (int off = 32; off > 0; off >>= 1) s += __shfl_xor(s, off, 64);
    if (c == 0) t[r] = TEMP * __logf(s) - mn;
}

// 1024 blocks x 4 waves x 8 pairs; block-level atomic + ticket: last block
// finalizes the loss.
__global__ __launch_bounds__(256)
void pair_fin_k(const float* __restrict__ x, const int* __restrict__ row,
                const int* __restrict__ col, const float* __restrict__ t,
                float* __restrict__ acc, unsigned* __restrict__ cnt,
                float* __restrict__ out) {
    const int lane = threadIdx.x & 63;
    const int wave = threadIdx.x >> 6;
    const int p0 = (blockIdx.x * 4 + wave) * 8;

    int rp[8], cp[8];
#pragma unroll
    for (int i = 0; i < 8; ++i) { rp[i] = row[p0 + i]; cp[i] = col[p0 + i]; }
    float4 a[8], b[8];
#pragma unroll
    for (int i = 0; i < 8; ++i) {
        a[i] = *(const float4*)&x[(size_t)rp[i] * D + lane * 4];
        b[i] = *(const float4*)&x[(size_t)cp[i] * D + lane * 4];
    }
    float wsum = 0.0f;
#pragma unroll
    for (int i = 0; i < 8; ++i) {
        float d = fabsf(a[i].x - b[i].x) + fabsf(a[i].y - b[i].y) +
                  fabsf(a[i].z - b[i].z) + fabsf(a[i].w - b[i].w);
#pragma unroll
        for (int off = 32; off > 0; off >>= 1) d += __shfl_xor(d, off, 64);
        if (lane == 0) wsum += d + t[rp[i]];
    }

    __shared__ float bs[4];
    if (lane == 0) bs[wave] = wsum;
    __syncthreads();
    if (threadIdx.x == 0) {
        const float tot = bs[0] + bs[1] + bs[2] + bs[3];
        atomicAdd(acc, tot);
        __threadfence();
        const unsigned tk = atomicAdd(cnt, 1u);
        if (tk == (unsigned)(gridDim.x - 1)) {
            const float v = atomicAdd(acc, 0.0f);  // coherent read
            out[0] = v * (1.0f / (float)NPOS);
        }
    }
}

extern "C" void kernel_launch(void* const* d_in, const int* in_sizes, int n_in,
                              void* d_out, int out_size, void* d_ws, size_t ws_size,
                              hipStream_t stream) {
    const float* x = (const float*)d_in[0];
    const int* row = (const int*)d_in[1];
    const int* col = (const int*)d_in[2];
    float* ws = (float*)d_ws;
    float* out = (float*)d_out;
    unsigned* xq = (unsigned*)(ws + WS_XQ);
    float* acc = ws + WS_ACC;
    unsigned* cnt = (unsigned*)(ws + WS_CNT);

    cvt_init_k<<<(N * D / 4) / 256, 256, 0, stream>>>(x, xq, acc, cnt);

    dist_tile_k<<<NTRI, 64, 0, stream>>>(xq, (float2*)(ws + WS_PSTAT));

    row_stats_k<<<N / 4, 256, 0, stream>>>((const float2*)(ws + WS_PSTAT), ws + WS_T);

    pair_fin_k<<<NPOS / 32, 256, 0, stream>>>(x, row, col, ws + WS_T, acc, cnt, out);
}

// Round 12
// 125.198 us; speedup vs baseline: 1.0724x; 1.0549x over previous
//
#include <hip/hip_runtime.h>
#include <math.h>

#define N 4096
#define D 256
#define NPOS 32768
#define TEMP 0.07f
#define INVT (1.0f / 0.07f)
#define BIGF 3.0e38f

#define RQ 5.5f                      // quantization range [-RQ, RQ]
#define QS (255.0f / (2.0f * RQ))    // f32 -> u8 scale
#define DEQ (2.0f * RQ / 255.0f)     // u8-units -> f32

#define NT 64                        // 64x64 tiles per dim
#define NTRI (NT * (NT + 1) / 2)     // 2080 triangle blocks
#define KC 16                        // u32 (k4) per D-chunk (=64 dims), 4 chunks
#define LP 68                        // LDS row stride in u32

// workspace layout (floats):
// [0 .. 2*N*64)       pstat[r][c] float2 (pmin, psum), r=row, c=64-col-tile
// [2*N*64 .. +N)      t[r]
// [.. +1]             loss accumulator (float)
// [.. +1]             ticket counter (uint)
// [WS_XQ ..)          xq: N*(D/4) u32 of packed u8 quants
#define WS_PSTAT 0
#define WS_T    (2 * N * NT)
#define WS_ACC  (2 * N * NT + N)
#define WS_CNT  (2 * N * NT + N + 1)
#define WS_XQ   (2 * N * NT + N + 4)   // 16B-aligned

__device__ __forceinline__ void sad_acc(unsigned a, unsigned b, unsigned& c) {
#if __has_builtin(__builtin_amdgcn_sad_u8)
    c = __builtin_amdgcn_sad_u8(a, b, c);
#else
    asm("v_sad_u8 %0, %1, %2, %0" : "+v"(c) : "v"(a), "v"(b));
#endif
}

__device__ __forceinline__ unsigned quant1(float v) {
    const float f = fminf(fmaxf((v + RQ) * QS, 0.0f), 255.0f);
    return (unsigned)__float2uint_rn(f);
}

// quantize f32 -> packed u8 (4/u32), and zero acc/ticket
__global__ __launch_bounds__(256)
void cvt_init_k(const float* __restrict__ x, unsigned* __restrict__ xq,
                float* __restrict__ acc, unsigned* __restrict__ cnt) {
    const int i = blockIdx.x * 256 + threadIdx.x;  // over N*D/4
    const float4 v = ((const float4*)x)[i];
    const unsigned q = quant1(v.x) | (quant1(v.y) << 8) |
                       (quant1(v.z) << 16) | (quant1(v.w) << 24);
    xq[i] = q;
    if (i == 0) { *acc = 0.0f; *cnt = 0u; }
}

// 64x64 tile per block, TWO waves (128 threads): wave w owns cols w*32..+31
// of the tile, all 64 rows (8x4 micro-tile per lane -> 32 acc regs).
// 4160 waves total = 4 waves/SIMD (vs 2 before) and ~32 freed VGPRs for
// fragment prefetch -> hides the LDS latency that capped R8-R11 at ~40us.
// LDS [k4][m] stride-68: staging writes 2-way (free), frag b128 reads
// 8 distinct addrs, 8-lane broadcast (conflict-free).
__global__ __launch_bounds__(128, 4)
void dist_tile_k(const unsigned* __restrict__ xq, float2* __restrict__ pstat) {
    // triangular decode: blockIdx.x -> (bm, bn), bm <= bn
    const int tt = blockIdx.x;
    const int u_ = (NTRI - 1) - tt;
    int r = (int)((sqrtf((float)(8 * u_ + 1)) - 1.0f) * 0.5f);
    while (r * (r + 1) / 2 > u_) --r;
    while ((r + 1) * (r + 2) / 2 <= u_) ++r;
    const int bm = (NT - 1) - r;                      // row tile
    const int bn = (NT - 1) - (u_ - r * (r + 1) / 2); // col tile
    const bool diag = (bm == bn);

    const int tid = threadIdx.x;    // 0..127
    const int lane = tid & 63;
    const int w = tid >> 6;         // wave: col half
    const int tx = lane & 7;
    const int ty = lane >> 3;

    __shared__ unsigned As[KC][LP];    // 4.35 KB
    __shared__ unsigned Bs[KC][LP];    // 4.35 KB
    __shared__ float rmin_s[2][64];
    __shared__ float rsum_s[2][64];

    unsigned uacc[2][4][4];  // [rh][i][j]: rows rh*32+ty*4+i, col w*32+tx*4+j
#pragma unroll
    for (int rh = 0; rh < 2; ++rh)
#pragma unroll
        for (int i = 0; i < 4; ++i)
#pragma unroll
            for (int j = 0; j < 4; ++j) uacc[rh][i][j] = 0u;

    const int rowA0 = bm * 64;
    const int rowB0 = bn * 64;

    // staging: sr = tid>>2 (0..31), su = tid&3; rows sr and sr+32
    const int sr = tid >> 2;
    const int su = tid & 3;
    const uint4* gA0 = (const uint4*)xq + (size_t)(rowA0 + sr) * 16 + su;
    const uint4* gA1 = (const uint4*)xq + (size_t)(rowA0 + sr + 32) * 16 + su;
    const uint4* gB0 = (const uint4*)xq + (size_t)(rowB0 + sr) * 16 + su;
    const uint4* gB1 = (const uint4*)xq + (size_t)(rowB0 + sr + 32) * 16 + su;

    const int boff = w * 32 + tx * 4;

    for (int chk = 0; chk < 4; ++chk) {
        const uint4 la0 = gA0[chk * 4];
        const uint4 la1 = gA1[chk * 4];
        const uint4 lb0 = gB0[chk * 4];
        const uint4 lb1 = gB1[chk * 4];
        __syncthreads();  // previous chunk's reads done before overwrite
        As[su * 4 + 0][sr] = la0.x; As[su * 4 + 1][sr] = la0.y;
        As[su * 4 + 2][sr] = la0.z; As[su * 4 + 3][sr] = la0.w;
        As[su * 4 + 0][sr + 32] = la1.x; As[su * 4 + 1][sr + 32] = la1.y;
        As[su * 4 + 2][sr + 32] = la1.z; As[su * 4 + 3][sr + 32] = la1.w;
        Bs[su * 4 + 0][sr] = lb0.x; Bs[su * 4 + 1][sr] = lb0.y;
        Bs[su * 4 + 2][sr] = lb0.z; Bs[su * 4 + 3][sr] = lb0.w;
        Bs[su * 4 + 0][sr + 32] = lb1.x; Bs[su * 4 + 1][sr + 32] = lb1.y;
        Bs[su * 4 + 2][sr + 32] = lb1.z; Bs[su * 4 + 3][sr + 32] = lb1.w;
        __syncthreads();

#pragma unroll
        for (int k4 = 0; k4 < KC; ++k4) {
            const uint4 alo = *(const uint4*)&As[k4][ty * 4];
            const uint4 ahi = *(const uint4*)&As[k4][32 + ty * 4];
            const uint4 bw = *(const uint4*)&Bs[k4][boff];
            const unsigned av[2][4] = {{alo.x, alo.y, alo.z, alo.w},
                                       {ahi.x, ahi.y, ahi.z, ahi.w}};
            const unsigned bv[4] = {bw.x, bw.y, bw.z, bw.w};
#pragma unroll
            for (int rh = 0; rh < 2; ++rh)
#pragma unroll
                for (int i = 0; i < 4; ++i)
#pragma unroll
                    for (int j = 0; j < 4; ++j)
                        sad_acc(av[rh][i], bv[j], uacc[rh][i][j]);
        }
    }

    // dequantize to float
    float acc[2][4][4];
#pragma unroll
    for (int rh = 0; rh < 2; ++rh)
#pragma unroll
        for (int i = 0; i < 4; ++i)
#pragma unroll
            for (int j = 0; j < 4; ++j)
                acc[rh][i][j] = (float)uacc[rh][i][j] * DEQ;

    // diagonal exclusion: poison self-distance (min skips it, exp -> 0)
    if (diag) {
#pragma unroll
        for (int rh = 0; rh < 2; ++rh)
#pragma unroll
            for (int i = 0; i < 4; ++i)
#pragma unroll
                for (int j = 0; j < 4; ++j)
                    if (rh * 32 + ty * 4 + i == w * 32 + tx * 4 + j)
                        acc[rh][i][j] = BIGF;
    }

    // ---- row stats: wave-local over 32 cols, then cross-wave LDS merge ----
#pragma unroll
    for (int rh = 0; rh < 2; ++rh) {
#pragma unroll
        for (int i = 0; i < 4; ++i) {
            float mn = BIGF;
#pragma unroll
            for (int j = 0; j < 4; ++j) mn = fminf(mn, acc[rh][i][j]);
            mn = fminf(mn, __shfl_xor(mn, 1, 64));
            mn = fminf(mn, __shfl_xor(mn, 2, 64));
            mn = fminf(mn, __shfl_xor(mn, 4, 64));
            float s = 0.0f;
#pragma unroll
            for (int j = 0; j < 4; ++j)
                s += __expf((mn - acc[rh][i][j]) * INVT);
            s += __shfl_xor(s, 1, 64);
            s += __shfl_xor(s, 2, 64);
            s += __shfl_xor(s, 4, 64);
            if (tx == 0) {
                rmin_s[w][rh * 32 + ty * 4 + i] = mn;
                rsum_s[w][rh * 32 + ty * 4 + i] = s;
            }
        }
    }

    // ---- col stats (iff bm < bn): wave-local over all 64 rows ----
    if (!diag) {
#pragma unroll
        for (int j = 0; j < 4; ++j) {
            float mn = BIGF;
#pragma unroll
            for (int rh = 0; rh < 2; ++rh)
#pragma unroll
                for (int i = 0; i < 4; ++i) mn = fminf(mn, acc[rh][i][j]);
            mn = fminf(mn, __shfl_xor(mn, 8, 64));
            mn = fminf(mn, __shfl_xor(mn, 16, 64));
            mn = fminf(mn, __shfl_xor(mn, 32, 64));
            float s = 0.0f;
#pragma unroll
            for (int rh = 0; rh < 2; ++rh)
#pragma unroll
                for (int i = 0; i < 4; ++i)
                    s += __expf((mn - acc[rh][i][j]) * INVT);
            s += __shfl_xor(s, 8, 64);
            s += __shfl_xor(s, 16, 64);
            s += __shfl_xor(s, 32, 64);
            if (ty == 0)
                pstat[(size_t)(rowB0 + w * 32 + tx * 4 + j) * NT + bm] =
                    make_float2(mn, s);
        }
    }

    __syncthreads();
    // merge the two col-halves' row stats; threads 0..63 each own one row
    if (tid < 64) {
        const float m0 = rmin_s[0][tid], m1 = rmin_s[1][tid];
        const float mn = fminf(m0, m1);
        const float s = rsum_s[0][tid] * __expf((mn - m0) * INVT) +
                        rsum_s[1][tid] * __expf((mn - m1) * INVT);
        pstat[(size_t)(rowA0 + tid) * NT + bn] = make_float2(mn, s);
    }
}

// One wave per row: coalesced float2 read of the 64 partials, shuffle reduce.
__global__ __launch_bounds__(256)
void row_stats_k(const float2* __restrict__ pstat, float* __restrict__ t) {
    const int r = blockIdx.x * 4 + (threadIdx.x >> 6);
    const int c = threadIdx.x & 63;
    const float2 p = pstat[(size_t)r * NT + c];
    float mn = p.x;
#pragma unroll
    for (int off = 32; off > 0; off >>= 1) mn = fminf(mn, __shfl_xor(mn, off, 64));
    float s = p.y * __expf((mn - p.x) * INVT);
#pragma unroll
    for (int off = 32; off > 0; off >>= 1) s += __shfl_xor(s, off, 64);
    if (c == 0) t[r] = TEMP * __logf(s) - mn;
}

// 1024 blocks x 4 waves x 8 pairs; block-level atomic + ticket: last block
// finalizes the loss.
__global__ __launch_bounds__(256)
void pair_fin_k(const float* __restrict__ x, const int* __restrict__ row,
                const int* __restrict__ col, const float* __restrict__ t,
                float* __restrict__ acc, unsigned* __restrict__ cnt,
                float* __restrict__ out) {
    const int lane = threadIdx.x & 63;
    const int wave = threadIdx.x >> 6;
    const int p0 = (blockIdx.x * 4 + wave) * 8;

    int rp[8], cp[8];
#pragma unroll
    for (int i = 0; i < 8; ++i) { rp[i] = row[p0 + i]; cp[i] = col[p0 + i]; }
    float4 a[8], b[8];
#pragma unroll
    for (int i = 0; i < 8; ++i) {
        a[i] = *(const float4*)&x[(size_t)rp[i] * D + lane * 4];
        b[i] = *(const float4*)&x[(size_t)cp[i] * D + lane * 4];
    }
    float wsum = 0.0f;
#pragma unroll
    for (int i = 0; i < 8; ++i) {
        float d = fabsf(a[i].x - b[i].x) + fabsf(a[i].y - b[i].y) +
                  fabsf(a[i].z - b[i].z) + fabsf(a[i].w - b[i].w);
#pragma unroll
        for (int off = 32; off > 0; off >>= 1) d += __shfl_xor(d, off, 64);
        if (lane == 0) wsum += d + t[rp[i]];
    }

    __shared__ float bs[4];
    if (lane == 0) bs[wave] = wsum;
    __syncthreads();
    if (threadIdx.x == 0) {
        const float tot = bs[0] + bs[1] + bs[2] + bs[3];
        atomicAdd(acc, tot);
        __threadfence();
        const unsigned tk = atomicAdd(cnt, 1u);
        if (tk == (unsigned)(gridDim.x - 1)) {
            const float v = atomicAdd(acc, 0.0f);  // coherent read
            out[0] = v * (1.0f / (float)NPOS);
        }
    }
}

extern "C" void kernel_launch(void* const* d_in, const int* in_sizes, int n_in,
                              void* d_out, int out_size, void* d_ws, size_t ws_size,
                              hipStream_t stream) {
    const float* x = (const float*)d_in[0];
    const int* row = (const int*)d_in[1];
    const int* col = (const int*)d_in[2];
    float* ws = (float*)d_ws;
    float* out = (float*)d_out;
    unsigned* xq = (unsigned*)(ws + WS_XQ);
    float* acc = ws + WS_ACC;
    unsigned* cnt = (unsigned*)(ws + WS_CNT);

    cvt_init_k<<<(N * D / 4) / 256, 256, 0, stream>>>(x, xq, acc, cnt);

    dist_tile_k<<<NTRI, 128, 0, stream>>>(xq, (float2*)(ws + WS_PSTAT));

    row_stats_k<<<N / 4, 256, 0, stream>>>((const float2*)(ws + WS_PSTAT), ws + WS_T);

    pair_fin_k<<<NPOS / 32, 256, 0, stream>>>(x, row, col, ws + WS_T, acc, cnt, out);
}